// Round 3
// baseline (276.520 us; speedup 1.0000x reference)
//
#include <hip/hip_runtime.h>
#include <cstdint>

constexpr int D = 256;     // D_IN == D_OUT
constexpr int TM = 128;    // m-rows per block; block covers full o=256

typedef __bf16 bf16x8 __attribute__((ext_vector_type(8)));
typedef float  f32x4  __attribute__((ext_vector_type(4)));

// ---- prep (single kernel, no atomics): one block per output row o -------
// W2[o,:] = W[o,:] + sum_{e: dst_e==o} W[src_e,:]  -> split bf16 hi/lo,
// frag-ordered:  idx = kc*8192 + (o16b*64 + (o&15) + 16*q)*8 + j
// b2[o] = b[o] + sum b[src_e]
__global__ void prep_kernel(const float* __restrict__ W, const float* __restrict__ b,
                            const int* __restrict__ em, int E,
                            ushort* __restrict__ Wh, ushort* __restrict__ Wl,
                            float* __restrict__ b2) {
    const int o = blockIdx.x;
    const int k = threadIdx.x;
    float acc  = W[o * D + k];
    float bacc = b[o];
    for (int e = 0; e < E; ++e) {            // E=1024, wave-uniform branch
        if (em[e] == o) {
            int src = em[E + e];
            acc  += W[src * D + k];
            bacc += b[src];
        }
    }
    uint32_t u  = __float_as_uint(acc);
    uint32_t hu = u & 0xFFFF0000u;           // hi = truncate (exact residual)
    float r = acc - __uint_as_float(hu);
    uint32_t ru = __float_as_uint(r);
    uint32_t lu = ru + 0x7FFFu + ((ru >> 16) & 1u);   // RNE lo
    int kc = k >> 5, kk = k & 31, q = kk >> 3, j = kk & 7;
    int idx = kc * 8192 + (((o >> 4) * 4 + q) * 16 + (o & 15)) * 8 + j;
    Wh[idx] = (ushort)(hu >> 16);
    Wl[idx] = (ushort)(lu >> 16);
    if (k == 0) b2[o] = bacc;
}

// ---- in-register fp32 -> bf16 hi/lo split (8 elems -> 2 uint4) ----------
__device__ __forceinline__ void cvt8(const float4& f0, const float4& f1,
                                     uint4& hi, uint4& lo) {
    float xs[8] = {f0.x, f0.y, f0.z, f0.w, f1.x, f1.y, f1.z, f1.w};
    uint32_t h[8], l[8];
    #pragma unroll
    for (int j = 0; j < 8; ++j) {
        uint32_t u  = __float_as_uint(xs[j]);
        uint32_t hu = u & 0xFFFF0000u;
        h[j] = hu;
        float r = xs[j] - __uint_as_float(hu);
        uint32_t ru = __float_as_uint(r);
        l[j] = ru + 0x7FFFu + ((ru >> 16) & 1u);
    }
    hi = make_uint4((h[0] >> 16) | (h[1] & 0xFFFF0000u),
                    (h[2] >> 16) | (h[3] & 0xFFFF0000u),
                    (h[4] >> 16) | (h[5] & 0xFFFF0000u),
                    (h[6] >> 16) | (h[7] & 0xFFFF0000u));
    lo = make_uint4((l[0] >> 16) | (l[1] & 0xFFFF0000u),
                    (l[2] >> 16) | (l[3] & 0xFFFF0000u),
                    (l[4] >> 16) | (l[5] & 0xFFFF0000u),
                    (l[6] >> 16) | (l[7] & 0xFFFF0000u));
}

// ---- main GEMM: block = m-128 x o-256, 4 waves (wave = m-128 x o-64) ----
// X: LDS double-buffered hi/lo bf16 frags, 1 barrier/kc.
// W: direct global->VGPR bf16x8 frag loads (L2-resident), prefetched 1 kc ahead.
__global__ __launch_bounds__(256, 2) void resgcn_mfma(
    const float* __restrict__ X, const ushort* __restrict__ Whg,
    const ushort* __restrict__ Wlg, const float* __restrict__ b2,
    const float* __restrict__ blen, float* __restrict__ out, int M)
{
    __shared__ alignas(16) ushort Xh[2][8][64][8];   // 16 KB
    __shared__ alignas(16) ushort Xl[2][8][64][8];   // 16 KB

    const int tid  = threadIdx.x;
    const int lane = tid & 63;
    const int w    = tid >> 6;                 // wave's o-quadrant
    const int m0   = blockIdx.x * TM;

    // X staging: thread covers row sm, k-half sh of each 32-k chunk
    const int sm = tid >> 1;
    const int sh = tid & 1;
    int srow = m0 + sm; if (srow >= M) srow = M - 1;   // clamp: real data
    const float* xrow = X + (size_t)srow * D + sh * 16;
    const int m16b = sm >> 4;
    const int mlow = sm & 15;
    const int q0 = sh * 2, q1 = sh * 2 + 1;

    // B frag pointers (frag-ordered global): o16b = w*4+b, stride 512 ushort
    const ushort* bbase_h = Whg + ((size_t)(w * 4) * 64 + lane) * 8;
    const ushort* bbase_l = Wlg + ((size_t)(w * 4) * 64 + lane) * 8;

    f32x4 acc[8][4];
    #pragma unroll
    for (int a = 0; a < 8; ++a)
        #pragma unroll
        for (int b = 0; b < 4; ++b) acc[a][b] = (f32x4){0.f, 0.f, 0.f, 0.f};

    bf16x8 bh[4], bl[4], nbh[4], nbl[4];

    // prologue: stage X kc=0 into buf0; load B kc=0
    {
        float4 f0 = *(const float4*)(xrow + 0);
        float4 f1 = *(const float4*)(xrow + 4);
        float4 f2 = *(const float4*)(xrow + 8);
        float4 f3 = *(const float4*)(xrow + 12);
        uint4 h0, l0, h1, l1;
        cvt8(f0, f1, h0, l0);
        cvt8(f2, f3, h1, l1);
        *(uint4*)&Xh[0][m16b][mlow + 16 * q0][0] = h0;
        *(uint4*)&Xl[0][m16b][mlow + 16 * q0][0] = l0;
        *(uint4*)&Xh[0][m16b][mlow + 16 * q1][0] = h1;
        *(uint4*)&Xl[0][m16b][mlow + 16 * q1][0] = l1;
    }
    #pragma unroll
    for (int b = 0; b < 4; ++b) {
        bh[b] = *(const bf16x8*)(bbase_h + b * 512);
        bl[b] = *(const bf16x8*)(bbase_l + b * 512);
    }
    __syncthreads();

    #pragma unroll 2
    for (int kc = 0; kc < 8; ++kc) {
        const int buf = kc & 1;

        // prefetch next kc: X raw fp32 + B frags (no LDS, no barrier dep)
        float4 f0, f1, f2, f3;
        if (kc < 7) {
            const float* p = xrow + (kc + 1) * 32;
            f0 = *(const float4*)(p + 0);
            f1 = *(const float4*)(p + 4);
            f2 = *(const float4*)(p + 8);
            f3 = *(const float4*)(p + 12);
            const ushort* gh = bbase_h + (size_t)(kc + 1) * 8192;
            const ushort* gl = bbase_l + (size_t)(kc + 1) * 8192;
            #pragma unroll
            for (int b = 0; b < 4; ++b) {
                nbh[b] = *(const bf16x8*)(gh + b * 512);
                nbl[b] = *(const bf16x8*)(gl + b * 512);
            }
        }

        // compute on current buffer
        #pragma unroll
        for (int a = 0; a < 8; ++a) {
            bf16x8 ah = *(const bf16x8*)&Xh[buf][a][lane][0];
            bf16x8 al = *(const bf16x8*)&Xl[buf][a][lane][0];
            #pragma unroll
            for (int b = 0; b < 4; ++b) {
                acc[a][b] = __builtin_amdgcn_mfma_f32_16x16x32_bf16(ah, bh[b], acc[a][b], 0, 0, 0);
                acc[a][b] = __builtin_amdgcn_mfma_f32_16x16x32_bf16(al, bh[b], acc[a][b], 0, 0, 0);
                acc[a][b] = __builtin_amdgcn_mfma_f32_16x16x32_bf16(ah, bl[b], acc[a][b], 0, 0, 0);
            }
        }

        // stage next X into other buffer; rotate B
        if (kc < 7) {
            uint4 h0, l0, h1, l1;
            cvt8(f0, f1, h0, l0);
            cvt8(f2, f3, h1, l1);
            *(uint4*)&Xh[buf ^ 1][m16b][mlow + 16 * q0][0] = h0;
            *(uint4*)&Xl[buf ^ 1][m16b][mlow + 16 * q0][0] = l0;
            *(uint4*)&Xh[buf ^ 1][m16b][mlow + 16 * q1][0] = h1;
            *(uint4*)&Xl[buf ^ 1][m16b][mlow + 16 * q1][0] = l1;
            #pragma unroll
            for (int b = 0; b < 4; ++b) { bh[b] = nbh[b]; bl[b] = nbl[b]; }
        }
        __syncthreads();
    }

    // epilogue: C/D layout col=lane&15, row=(lane>>4)*4+reg
    const int col = lane & 15;
    const int rq  = lane >> 4;
    float bias[4];
    #pragma unroll
    for (int b = 0; b < 4; ++b) bias[b] = b2[(w * 4 + b) * 16 + col];

    #pragma unroll
    for (int a = 0; a < 8; ++a) {
        #pragma unroll
        for (int r = 0; r < 4; ++r) {
            int m = m0 + a * 16 + rq * 4 + r;
            if (m < M) {
                float inv = 1.0f / blen[m];
                #pragma unroll
                for (int b = 0; b < 4; ++b) {
                    int o = (w * 4 + b) * 16 + col;
                    out[(size_t)m * D + o] = (acc[a][b][r] + bias[b]) * inv;
                }
            }
        }
    }
}

extern "C" void kernel_launch(void* const* d_in, const int* in_sizes, int n_in,
                              void* d_out, int out_size, void* d_ws, size_t ws_size,
                              hipStream_t stream) {
    (void)n_in; (void)out_size; (void)ws_size;
    const float* X  = (const float*)d_in[0];
    const float* W  = (const float*)d_in[1];
    const float* b  = (const float*)d_in[2];
    const int*   em = (const int*)d_in[3];
    const float* bl = (const float*)d_in[4];
    float* out = (float*)d_out;

    const int M = in_sizes[0] / D;
    const int E = in_sizes[3] / 2;

    ushort* Wh = (ushort*)d_ws;          // 65536 bf16
    ushort* Wl = Wh + D * D;             // 65536 bf16
    float*  b2 = (float*)(Wl + D * D);   // 256 fp32

    prep_kernel<<<D, D, 0, stream>>>(W, b, em, E, Wh, Wl, b2);

    int mblocks = (M + TM - 1) / TM;
    resgcn_mfma<<<mblocks, 256, 0, stream>>>(X, Wh, Wl, b2, bl, out, M);
}

// Round 4
// 232.315 us; speedup vs baseline: 1.1903x; 1.1903x over previous
//
#include <hip/hip_runtime.h>
#include <cstdint>

constexpr int D = 256;

typedef __bf16 bf16x8 __attribute__((ext_vector_type(8)));
typedef float  f32x4  __attribute__((ext_vector_type(4)));

// ---- prep 1: W2 = W (fp32), b2 = b ------------------------------------
__global__ void prep_copy(const float* __restrict__ W, const float* __restrict__ b,
                          float* __restrict__ W2, float* __restrict__ b2) {
    int i = blockIdx.x * 256 + threadIdx.x;
    W2[i] = W[i];
    if (blockIdx.x == 0) b2[threadIdx.x] = b[threadIdx.x];
}

// ---- prep 2: per edge e: W2[dst,:] += W[src,:]; b2[dst] += b[src] ------
__global__ void prep_edges(const int* __restrict__ em, int E,
                           const float* __restrict__ W, const float* __restrict__ b,
                           float* __restrict__ W2, float* __restrict__ b2) {
    int e = blockIdx.x;
    int k = threadIdx.x;
    int dst = em[e];
    int src = em[E + e];
    atomicAdd(&W2[dst * D + k], W[src * D + k]);
    if (k == 0) atomicAdd(&b2[dst], b[src]);
}

// ---- prep 3: W2 fp32 -> RNE bf16, frag-order --------------------------
// B-frag (16x16x32): lane holds B[o16b*16 + (lane&15)][kc*32 + (lane>>4)*8 + j]
// idx = kc*8192 + (o16b*64 + (o&15) + 16*q)*8 + j
__global__ void prep_convert(const float* __restrict__ W2, ushort* __restrict__ Wh) {
    int i = blockIdx.x * 256 + threadIdx.x;   // i = o*256 + k
    int o = i >> 8, k = i & 255;
    uint32_t u = __float_as_uint(W2[i]);
    uint32_t r = u + 0x7FFFu + ((u >> 16) & 1u);   // RNE to bf16
    int kc = k >> 5, kk = k & 31, q = kk >> 3, j = kk & 7;
    int idx = kc * 8192 + (((o >> 4) * 4 + q) * 16 + (o & 15)) * 8 + j;
    Wh[idx] = (ushort)(r >> 16);
}

// ---- fp32x8 -> bf16 hi (trunc, exact residual) + lo (RNE) -------------
__device__ __forceinline__ void cvt8(const float4& f0, const float4& f1,
                                     bf16x8& hi8, bf16x8& lo8) {
    float xs[8] = {f0.x, f0.y, f0.z, f0.w, f1.x, f1.y, f1.z, f1.w};
    uint32_t h[8], l[8];
    #pragma unroll
    for (int j = 0; j < 8; ++j) {
        uint32_t u  = __float_as_uint(xs[j]);
        uint32_t hu = u & 0xFFFF0000u;
        h[j] = hu;
        float r = xs[j] - __uint_as_float(hu);
        uint32_t ru = __float_as_uint(r);
        l[j] = ru + 0x7FFFu + ((ru >> 16) & 1u);
    }
    uint4 hp = make_uint4((h[0] >> 16) | (h[1] & 0xFFFF0000u),
                          (h[2] >> 16) | (h[3] & 0xFFFF0000u),
                          (h[4] >> 16) | (h[5] & 0xFFFF0000u),
                          (h[6] >> 16) | (h[7] & 0xFFFF0000u));
    uint4 lp = make_uint4((l[0] >> 16) | (l[1] & 0xFFFF0000u),
                          (l[2] >> 16) | (l[3] & 0xFFFF0000u),
                          (l[4] >> 16) | (l[5] & 0xFFFF0000u),
                          (l[6] >> 16) | (l[7] & 0xFFFF0000u));
    hi8 = *(bf16x8*)&hp;
    lo8 = *(bf16x8*)&lp;
}

// ---- main GEMM: no LDS, no barriers. ----------------------------------
// Block = 256 thr = 4 waves; block tile m-128 x o-128 (bid&1 picks o-half).
// Wave tile m-64 x o-64: acc[4][4] f32x4 = 64 AGPRs.
// A frags loaded straight global->VGPR in frag pattern, cvt to bf16 hi/lo.
// W (bf16 RNE, frag-ordered, L2-resident) loaded straight global->VGPR.
// out = x_hi.Wh + x_lo.Wh  (W-lo dropped: err ~7e-3 << tolerance)
__global__ __launch_bounds__(256) void resgcn_mfma(
    const float* __restrict__ X, const ushort* __restrict__ Whg,
    const float* __restrict__ b2, const float* __restrict__ blen,
    float* __restrict__ out, int M)
{
    const int tid  = threadIdx.x;
    const int lane = tid & 63;
    const int w    = tid >> 6;
    const int wm   = w >> 1;           // wave's m-half within block
    const int wo   = w & 1;            // wave's o-half within block-half
    const int bid  = blockIdx.x;
    const int ob   = bid & 1;          // o 128-half
    const int mb   = bid >> 1;

    const int m0 = mb * 128 + wm * 64;
    const int ob16 = ob * 8 + wo * 4;  // first o16-block of this wave

    // A-frag row pointers: frag a covers rows m0+a*16+(lane&15), k-quad lane>>4
    const float* pA[4];
    #pragma unroll
    for (int a = 0; a < 4; ++a) {
        int r = m0 + a * 16 + (lane & 15);
        if (r >= M) r = M - 1;                       // clamp: real data, no NaN
        pA[a] = X + (size_t)r * D + ((lane >> 4) * 8);
    }
    const ushort* pB = Whg + ((size_t)ob16 * 64 + lane) * 8;

    f32x4 acc[4][4];
    #pragma unroll
    for (int a = 0; a < 4; ++a)
        #pragma unroll
        for (int b = 0; b < 4; ++b) acc[a][b] = (f32x4){0.f, 0.f, 0.f, 0.f};

    float4 xa[4][2];
    bf16x8 bf[4];
    #pragma unroll
    for (int a = 0; a < 4; ++a) {
        xa[a][0] = *(const float4*)(pA[a]);
        xa[a][1] = *(const float4*)(pA[a] + 4);
    }
    #pragma unroll
    for (int b = 0; b < 4; ++b) bf[b] = *(const bf16x8*)(pB + b * 512);

    for (int kc = 0; kc < 8; ++kc) {
        // prefetch kc+1 (pure vmcnt pipeline, no barriers anywhere)
        float4 nxa[4][2];
        bf16x8 nbf[4];
        if (kc < 7) {
            #pragma unroll
            for (int a = 0; a < 4; ++a) {
                const float* p = pA[a] + (kc + 1) * 32;
                nxa[a][0] = *(const float4*)(p);
                nxa[a][1] = *(const float4*)(p + 4);
            }
            const ushort* q = pB + (size_t)(kc + 1) * 8192;
            #pragma unroll
            for (int b = 0; b < 4; ++b) nbf[b] = *(const bf16x8*)(q + b * 512);
        }

        // convert current X to hi/lo frags, then MFMA
        bf16x8 ah[4], al[4];
        #pragma unroll
        for (int a = 0; a < 4; ++a) cvt8(xa[a][0], xa[a][1], ah[a], al[a]);

        #pragma unroll
        for (int a = 0; a < 4; ++a)
            #pragma unroll
            for (int b = 0; b < 4; ++b) {
                acc[a][b] = __builtin_amdgcn_mfma_f32_16x16x32_bf16(ah[a], bf[b], acc[a][b], 0, 0, 0);
                acc[a][b] = __builtin_amdgcn_mfma_f32_16x16x32_bf16(al[a], bf[b], acc[a][b], 0, 0, 0);
            }

        if (kc < 7) {
            #pragma unroll
            for (int a = 0; a < 4; ++a) { xa[a][0] = nxa[a][0]; xa[a][1] = nxa[a][1]; }
            #pragma unroll
            for (int b = 0; b < 4; ++b) bf[b] = nbf[b];
        }
    }

    // epilogue: C/D layout col=lane&15, row=(lane>>4)*4+reg
    const int col = lane & 15;
    const int rq  = lane >> 4;
    float bias[4];
    #pragma unroll
    for (int b = 0; b < 4; ++b) bias[b] = b2[(ob16 + b) * 16 + col];

    #pragma unroll
    for (int a = 0; a < 4; ++a) {
        #pragma unroll
        for (int r = 0; r < 4; ++r) {
            int m = m0 + a * 16 + rq * 4 + r;
            if (m < M) {
                float inv = 1.0f / blen[m];
                #pragma unroll
                for (int b = 0; b < 4; ++b) {
                    int o = (ob16 + b) * 16 + col;
                    out[(size_t)m * D + o] = (acc[a][b][r] + bias[b]) * inv;
                }
            }
        }
    }
}

extern "C" void kernel_launch(void* const* d_in, const int* in_sizes, int n_in,
                              void* d_out, int out_size, void* d_ws, size_t ws_size,
                              hipStream_t stream) {
    (void)n_in; (void)out_size; (void)ws_size;
    const float* X  = (const float*)d_in[0];
    const float* W  = (const float*)d_in[1];
    const float* b  = (const float*)d_in[2];
    const int*   em = (const int*)d_in[3];
    const float* bl = (const float*)d_in[4];
    float* out = (float*)d_out;

    const int M = in_sizes[0] / D;
    const int E = in_sizes[3] / 2;

    float*  W2 = (float*)d_ws;           // 65536 fp32
    float*  b2 = W2 + D * D;             // 256 fp32
    ushort* Wh = (ushort*)(b2 + D);      // 65536 bf16, frag-ordered

    prep_copy<<<D * D / 256, 256, 0, stream>>>(W, b, W2, b2);
    prep_edges<<<E, D, 0, stream>>>(em, E, W, b, W2, b2);
    prep_convert<<<D * D / 256, 256, 0, stream>>>(W2, Wh);

    int mblocks = (M + 127) / 128;
    resgcn_mfma<<<mblocks * 2, 256, 0, stream>>>(X, Wh, b2, bl, out, M);
}